// Round 1
// baseline (172.102 us; speedup 1.0000x reference)
//
#include <hip/hip_runtime.h>
#include <hip/hip_bf16.h>

// ---------------------------------------------------------------------------
// Fused temporal multi-head attention for skeleton data (MI355X / gfx950).
// B=256, S=176 (8 time * 22 joints), D_in=128, H=8, Hd=32.
// One workgroup per (b, h): everything (x_b, W-slices, Q,K,V, P) lives in LDS.
// bf16 MFMA (16x16x32) for all three GEMMs; fp32 accumulate + fp32 softmax.
// ---------------------------------------------------------------------------

#define TIME_LEN 8
#define JOINTS   22
#define SEQ      176          // 11 tiles of 16
#define HN       8
#define HD       32
#define DIN      128
#define DMODEL   256

typedef unsigned short ushort_t;
typedef __attribute__((ext_vector_type(8))) short short8;
typedef __attribute__((ext_vector_type(4))) float float4v;

// LDS layout (ushort elements):
//   XS : [176][136]  x_b bf16                 @ 0      (23936)   } phase 0/1
//   WT : [3][32][136] W slices, transposed    @ 23936  (13056)   } phase 0/1
//   PS : [11][16][200] per-wave P matrix      @ 0      (35200)   } phase 2 (reuses XS/WT)
//   QS : [176][40]   Q bf16 (pre-scaled)      @ 36992  (7040)
//   KS : [176][40]   K bf16                   @ 44032  (7040)
//   VT : [32][200]   V bf16 transposed        @ 51072  (6400)
// total 57472 ushort = 114944 B  (<160 KiB, 1 block/CU)
#define SMEM_TOTAL 57472
#define OFF_WT 23936
#define OFF_QS 36992
#define OFF_KS 44032
#define OFF_VT 51072

__device__ __forceinline__ ushort_t f2bf(float f) {
    union { float f; unsigned int u; } c; c.f = f;
    unsigned int u = c.u;
    unsigned int rb = 0x7FFFu + ((u >> 16) & 1u);   // round-to-nearest-even
    return (ushort_t)((u + rb) >> 16);
}

__global__ __launch_bounds__(704, 1)
void attn_fused_kernel(const float* __restrict__ x,
                       const float* __restrict__ Wq, const float* __restrict__ bq,
                       const float* __restrict__ Wk, const float* __restrict__ bk,
                       const float* __restrict__ Wv, const float* __restrict__ bv,
                       float* __restrict__ out)
{
    __shared__ ushort_t smem[SMEM_TOTAL];
    ushort_t* XS = smem;             // [176][136]
    ushort_t* WT = smem + OFF_WT;    // [3][32][136]
    ushort_t* PS = smem;             // [11][16][200]  (phase 2)
    ushort_t* QS = smem + OFF_QS;    // [176][40]
    ushort_t* KS = smem + OFF_KS;    // [176][40]
    ushort_t* VT = smem + OFF_VT;    // [32][200]

    const int tid   = threadIdx.x;
    const int lane  = tid & 63;
    const int wave  = tid >> 6;      // 0..10
    const int col16 = lane & 15;
    const int quad  = lane >> 4;     // 0..3
    const int b     = blockIdx.x >> 3;
    const int h     = blockIdx.x & 7;

    // ---------------- Phase 0: cooperative staging ----------------
    // x_b [176][128] fp32 -> XS bf16, float4 loads (5632 float4 = 704*8 exact)
    const float* xb = x + (size_t)b * SEQ * DIN;
#pragma unroll
    for (int i = 0; i < 8; ++i) {
        int f4   = tid + i * 704;
        int flat = f4 * 4;
        int row  = flat >> 7;        // /128
        int col  = flat & 127;
        float4 v = reinterpret_cast<const float4*>(xb)[f4];
        ushort_t* dst = XS + row * 136 + col;
        dst[0] = f2bf(v.x); dst[1] = f2bf(v.y);
        dst[2] = f2bf(v.z); dst[3] = f2bf(v.w);
    }
    // W head-slices -> WT[mat][n][k] (transposed so B-operand reads are contiguous)
    // 3 * 32 * 128 = 12288 elems; coalesced over n within each k-row
    for (int i = 0; i < 18; ++i) {
        int idx = tid + i * 704;
        if (idx < 12288) {
            int mat = idx >> 12;
            int rem = idx & 4095;
            int k = rem >> 5, n = rem & 31;
            const float* W = (mat == 0) ? Wq : ((mat == 1) ? Wk : Wv);
            WT[mat * 4352 + n * 136 + k] = f2bf(W[k * DMODEL + h * HD + n]);
        }
    }
    // zero VT pad columns [176..200) so the last PV K-tile multiplies zeros
    if (tid < 768) {
        int r = tid / 24, c = 176 + tid % 24;
        VT[r * 200 + c] = 0;
    }
    __syncthreads();

    // ---------------- Phase 1: QKV projection (66 MFMA tile-jobs, 6/wave) ----
    const float kScale = 0.17677669529663687f;  // 1/sqrt(32)
#pragma unroll
    for (int i = 0; i < 6; ++i) {
        int j   = wave * 6 + i;      // 0..65
        int mat = j / 22;            // 0=Q 1=K 2=V
        int rem = j - mat * 22;
        int mt  = rem >> 1;          // M tile 0..10 (seq)
        int nt  = rem & 1;           // N tile 0..1  (feature)
        const ushort_t* xptr = XS + (mt * 16 + col16) * 136 + quad * 8;
        const ushort_t* wptr = WT + mat * 4352 + (nt * 16 + col16) * 136 + quad * 8;
        float4v acc = {0.f, 0.f, 0.f, 0.f};
#pragma unroll
        for (int kk = 0; kk < 4; ++kk) {
            short8 a  = *reinterpret_cast<const short8*>(xptr + kk * 32);
            short8 bf = *reinterpret_cast<const short8*>(wptr + kk * 32);
            acc = __builtin_amdgcn_mfma_f32_16x16x32_bf16(a, bf, acc, 0, 0, 0);
        }
        const float* bias = (mat == 0) ? bq : ((mat == 1) ? bk : bv);
        float bia = bias[h * HD + nt * 16 + col16];
        if (mat == 2) {
            int d = nt * 16 + col16;
#pragma unroll
            for (int r = 0; r < 4; ++r) {
                int t = mt * 16 + quad * 4 + r;
                float v = acc[r] + bia;
                v = v > 0.f ? v : 0.f;                   // ReLU on V
                VT[d * 200 + t] = f2bf(v);               // store transposed
            }
        } else {
            ushort_t* dstm = (mat == 0) ? QS : KS;
            float s = (mat == 0) ? kScale : 1.0f;        // fold 1/sqrt(Hd) into Q
#pragma unroll
            for (int r = 0; r < 4; ++r) {
                int t = mt * 16 + quad * 4 + r;
                dstm[t * 40 + nt * 16 + col16] = f2bf((acc[r] + bia) * s);
            }
        }
    }
    __syncthreads();

    // ---------------- Phase 2: attention, one 16-row Q tile per wave ----------
    const int w = wave;  // row tile 0..10
    // Q A-fragment (K = Hd = 32: single MFMA per score tile)
    short8 afrag = *reinterpret_cast<const short8*>(QS + (w * 16 + col16) * 40 + quad * 8);
    float4v sc[11];
#pragma unroll
    for (int n = 0; n < 11; ++n) {
        short8 bfrag = *reinterpret_cast<const short8*>(KS + (n * 16 + col16) * 40 + quad * 8);
        float4v z = {0.f, 0.f, 0.f, 0.f};
        sc[n] = __builtin_amdgcn_mfma_f32_16x16x32_bf16(afrag, bfrag, z, 0, 0, 0);
    }
    // mask: same time-block (22-joint frame) off-diagonal entries -> -inf
#pragma unroll
    for (int r = 0; r < 4; ++r) {
        int rg = w * 16 + quad * 4 + r;
        int rb = rg / 22;
#pragma unroll
        for (int n = 0; n < 11; ++n) {
            int cg = n * 16 + col16;
            int cb = cg / 22;
            if (cb == rb && cg != rg) sc[n][r] = -1e30f;
        }
    }
    // softmax per row (row = quad*4+r; its 176 cols live in 16 lanes x 11 regs)
#pragma unroll
    for (int r = 0; r < 4; ++r) {
        float mx = sc[0][r];
#pragma unroll
        for (int n = 1; n < 11; ++n) mx = fmaxf(mx, sc[n][r]);
        for (int off = 1; off < 16; off <<= 1) mx = fmaxf(mx, __shfl_xor(mx, off, 64));
        float sum = 0.f;
#pragma unroll
        for (int n = 0; n < 11; ++n) {
            float e = __expf(sc[n][r] - mx);
            sc[n][r] = e;
            sum += e;
        }
        for (int off = 1; off < 16; off <<= 1) sum += __shfl_xor(sum, off, 64);
        float inv = 1.0f / sum;
#pragma unroll
        for (int n = 0; n < 11; ++n) sc[n][r] *= inv;
    }
    // write P to this wave's LDS region in A-operand layout source (row-major)
    ushort_t* psw = PS + w * 3200;   // [16][200]
#pragma unroll
    for (int n = 0; n < 11; ++n)
#pragma unroll
        for (int r = 0; r < 4; ++r)
            psw[(quad * 4 + r) * 200 + n * 16 + col16] = f2bf(sc[n][r]);
    // zero pad cols [176..200) (6 iters, uniform across all lanes/waves)
    for (int idx = lane; idx < 16 * 24; idx += 64) {
        int rr = idx / 24, cc = 176 + idx % 24;
        psw[rr * 200 + cc] = 0;
    }
    __syncthreads();   // uniform; guarantees cross-lane LDS visibility

    // PV: out tile [16 x 32], K = 192 (padded) in 6 MFMA steps
    float4v o0 = {0.f, 0.f, 0.f, 0.f}, o1 = {0.f, 0.f, 0.f, 0.f};
    const ushort_t* prow = psw + col16 * 200;
    const ushort_t* v0p  = VT + col16 * 200;
    const ushort_t* v1p  = VT + (16 + col16) * 200;
#pragma unroll
    for (int kk = 0; kk < 6; ++kk) {
        short8 pa  = *reinterpret_cast<const short8*>(prow + kk * 32 + quad * 8);
        short8 vb0 = *reinterpret_cast<const short8*>(v0p + kk * 32 + quad * 8);
        short8 vb1 = *reinterpret_cast<const short8*>(v1p + kk * 32 + quad * 8);
        o0 = __builtin_amdgcn_mfma_f32_16x16x32_bf16(pa, vb0, o0, 0, 0, 0);
        o1 = __builtin_amdgcn_mfma_f32_16x16x32_bf16(pa, vb1, o1, 0, 0, 0);
    }
    // epilogue: out[b][s][h*32 + d], fp32
    float* ob = out + ((size_t)b * SEQ + w * 16) * DMODEL + h * HD;
#pragma unroll
    for (int r = 0; r < 4; ++r) {
        ob[(quad * 4 + r) * DMODEL + col16]      = o0[r];
        ob[(quad * 4 + r) * DMODEL + 16 + col16] = o1[r];
    }
}

extern "C" void kernel_launch(void* const* d_in, const int* in_sizes, int n_in,
                              void* d_out, int out_size, void* d_ws, size_t ws_size,
                              hipStream_t stream) {
    const float* x  = (const float*)d_in[0];
    const float* Wq = (const float*)d_in[1];
    const float* bq = (const float*)d_in[2];
    const float* Wk = (const float*)d_in[3];
    const float* bk = (const float*)d_in[4];
    const float* Wv = (const float*)d_in[5];
    const float* bv = (const float*)d_in[6];
    float* out = (float*)d_out;

    attn_fused_kernel<<<dim3(256 * HN), dim3(704), 0, stream>>>(
        x, Wq, bq, Wk, bk, Wv, bv, out);
}